// Round 15
// baseline (157.377 us; speedup 1.0000x reference)
//
#include <hip/hip_runtime.h>
#include <hip/hip_bf16.h>
#include <cstdint>

#define OUT_S_OFF 33554432ull   // 8*4096*64*16

typedef short s16x8 __attribute__((ext_vector_type(8)));
typedef float f32x4 __attribute__((ext_vector_type(4)));
typedef unsigned int u32x2 __attribute__((ext_vector_type(2)));

// ---------------- compile-time geometric algebra tables ----------------
constexpr int BM_[16]   = {0,1,2,4,8,3,5,9,6,10,12,7,11,13,14,15};
constexpr int IDXm_[16] = {0,1,2,5,3,6,8,11,4,7,9,12,10,13,14,15};
constexpr int G_[16]    = {0,1,1,1,1,2,2,2,2,2,2,3,3,3,3,4};
constexpr int SRC_[16]  = {0,0,2,3,4,2,3,4,8,9,10,8,9,10,14,14};
constexpr int HASP_[16] = {0,1,0,0,0,1,1,1,0,0,0,1,1,1,0,1};
constexpr int A2_[16]   = {0,5,0,0,0,6,6,6,0,0,0,7,7,7,0,8};
constexpr int GSTART[5] = {0,1,5,11,15};
constexpr int GCNT[5]   = {1,4,6,4,1};

constexpr int pcnt_(int x){ int c=0; for(int b=0;b<8;b++) c += (x>>b)&1; return c; }
constexpr int par_(int A,int B){ int sw=0; for(int b=0;b<4;b++) if((B>>b)&1) sw += pcnt_(A>>(b+1)); return (sw&1)?-1:1; }
constexpr int sgnv_(int b){ return par_(BM_[b], 15 & ~BM_[b]); }

struct GTab { int cnt[16]; signed char jj[16][16]; signed char kk[16][16]; signed char ss[16][16]; };

constexpr GTab mk_cayley(){
  GTab t{};
  for(int j=0;j<16;j++) for(int k=0;k<16;k++){
    int A=BM_[j], B=BM_[k];
    if(A & B & 1) continue;
    int i = IDXm_[A^B]; int s = par_(A,B);
    int n = t.cnt[i]; t.jj[i][n]=(signed char)j; t.kk[i][n]=(signed char)k; t.ss[i][n]=(signed char)s; t.cnt[i]=n+1;
  }
  return t;
}
constexpr GTab mk_join(){
  GTab t{};
  for(int j=0;j<16;j++) for(int k=0;k<16;k++){
    int cj = 15 & ~BM_[j], ck = 15 & ~BM_[k];
    if(cj & ck) continue;
    int m  = cj | ck;
    int w  = par_(cj, ck);
    int mp = IDXm_[15 & ~m];
    int s  = sgnv_(j)*sgnv_(k)*w*sgnv_(mp);
    int n = t.cnt[mp]; t.jj[mp][n]=(signed char)j; t.kk[mp][n]=(signed char)k; t.ss[mp][n]=(signed char)s; t.cnt[mp]=n+1;
  }
  return t;
}

__device__ __forceinline__ unsigned short f2bf(float f){   // prepack only
  unsigned u = __float_as_uint(f);
  return (unsigned short)((u + 0x7fffu + ((u>>16)&1u)) >> 16);
}
__device__ __forceinline__ unsigned int pack2(float a, float b){
  float2 v; v.x = a; v.y = b;
  __hip_bfloat162 h = __float22bfloat162_rn(v);
  union { __hip_bfloat162 h2; unsigned int u; } cv; cv.h2 = h; return cv.u;
}
__device__ __forceinline__ unsigned short f2bfh(float f){
  __hip_bfloat16 h = __float2bfloat16(f);
  union { __hip_bfloat16 hb; unsigned short u; } cv; cv.hb = h; return cv.u;
}

// ---------------- slab-indexed prepacked weights (B-operand fragments) ----------------
__device__ unsigned short g_WinSlab [4*9*2*2*512]; // [m][d 0..8][s 0..1][h]  (147KB)
__device__ unsigned short g_WinS2   [4*2*2*512];   // [m][s][h]               (16KB)
__device__ unsigned short g_WoutSlab[9*2*4*512];   // [d][s][nt]              (72KB)
__device__ unsigned short g_WoutS2  [4*4*512];     // [ss][nt]                (16KB)
__device__ unsigned short g_WsB     [6*4*512];     // [s 0..5][nt]            (24KB)

// Coalesced prepack: each thread reads contiguous 32-288B runs; each wave's
// stores land as 1KB contiguous lines per slab. Replaces the stride-36B
// gather version (ran every replay inside the headline, est. 10-15us).
__global__ __launch_bounds__(256) void prepack(
    const float* wL, const float* wR, const float* wJL, const float* wJR, const float* wO,
    const float* s2L, const float* s2R, const float* s2JL, const float* s2JR,
    const float* s2O, const float* mv2s, const float* s2s)
{
  int idx = blockIdx.x*256 + threadIdx.x;
  if (idx < 1024) {                          // g_WinSlab: (m,s,h,l) x inner (d,j)
    int l = idx&63, h=(idx>>6)&1, s=(idx>>7)&1, m=(idx>>8)&3;
    int y = h*16 + (l&15), kb = s*32 + ((l>>4)&3)*8;
    const float* w = (m==0)?wL:(m==1)?wR:(m==2)?wJL:wJR;
    unsigned short buf[9][8];
    #pragma unroll
    for (int j=0;j<8;j++){
      const float* src = w + (size_t)(y*64+kb+j)*9;
      #pragma unroll
      for (int d=0;d<9;d++) buf[d][j] = f2bf(src[d]);
    }
    #pragma unroll
    for (int d=0;d<9;d++)
      *(s16x8*)&g_WinSlab[((((m*9+d)*2+s)*2+h)*512) + l*8] = *(const s16x8*)buf[d];
  } else if (idx < 2048) {                   // g_WinS2
    int r = idx-1024;
    int l = r&63, h=(r>>6)&1, s=(r>>7)&1, m=(r>>8)&3;
    int y = h*16 + (l&15), kb = s*32 + ((l>>4)&3)*8;
    const float* s2 = (m==0)?s2L:(m==1)?s2R:(m==2)?s2JL:s2JR;
    unsigned short buf[8];
    #pragma unroll
    for (int j=0;j<8;j++) buf[j] = f2bf(s2[y*64 + kb + j]);
    *(s16x8*)&g_WinS2[(((m*2+s)*2+h)*512) + l*8] = *(const s16x8*)buf;
  } else if (idx < 2560) {                   // g_WoutSlab: (s,nt,l) x inner (d,j)
    int r = idx-2048;
    int l = r&63, nt=(r>>6)&3, s=(r>>8)&1;
    int y = nt*16 + (l&15), kb = s*32 + ((l>>4)&3)*8;
    unsigned short buf[9][8];
    #pragma unroll
    for (int j=0;j<8;j++){
      const float* src = wO + (size_t)(y*64+kb+j)*9;
      #pragma unroll
      for (int d=0;d<9;d++) buf[d][j] = f2bf(src[d]);
    }
    #pragma unroll
    for (int d=0;d<9;d++)
      *(s16x8*)&g_WoutSlab[(((d*2+s)*4+nt)*512) + l*8] = *(const s16x8*)buf[d];
  } else if (idx < 2816) {                   // g_WoutS2: (nt,l) x inner (ss,j)
    int r = idx-2560;
    int l = r&63, nt=(r>>6)&3;
    int y = nt*16 + (l&15), kb = ((l>>4)&3)*8;
    #pragma unroll
    for (int ss=0;ss<4;ss++){
      unsigned short buf[8];
      #pragma unroll
      for (int j=0;j<8;j++) buf[j] = f2bf(s2O[y*128 + ss*32 + kb + j]);
      *(s16x8*)&g_WoutS2[((ss*4+nt)*512) + l*8] = *(const s16x8*)buf;
    }
  } else if (idx < 4352) {                   // g_WsB: (s6,nt,l) x inner j
    int r = idx-2816;
    int l = r&63, nt=(r>>6)&3, s6=r>>8;
    int y = nt*16 + (l&15), kb = ((l>>4)&3)*8;
    unsigned short buf[8];
    #pragma unroll
    for (int j=0;j<8;j++){
      float v = (s6<2) ? mv2s[y*64 + s6*32 + kb + j] : s2s[y*128 + (s6-2)*32 + kb + j];
      buf[j] = f2bf(v);
    }
    *(s16x8*)&g_WsB[((s6*4+nt)*512) + l*8] = *(const s16x8*)buf;
  }
}

// ---------------- fused main kernel (persistent, 2 tiles/block) ----------------
// 1024 blocks x 2 tiles of 16 tokens; dual LDS buffers. Tile1's mv1+scalars are
// issued DURING tile0's P1a (land in the idle buffer) -> tile1 starts with zero
// input stall; HBM requests spread across the block lifetime. No launch-bounds
// cap beyond (256,2) (R4/6/7/11: tighter caps spill); no deep striding (R12's
// 4-tile version thrashed L3 and spilled).
// Roles: P1/P2 (g=wv>>1: 0=gp(L,R), 1=join(JL,JR)) x (h=wv&1); P3: nt=wv.
// Token's 64B output line stored back-to-back (R9: split => 2.4x write ampl).
__global__ __launch_bounds__(256, 2) void fused(
    const float* __restrict__ mv1, const float* __restrict__ mv2,
    const float* __restrict__ sc1, const float* __restrict__ sc2,
    const float* __restrict__ refmv, const float* __restrict__ bias,
    float* __restrict__ out)
{
  __shared__ unsigned int s_mv[2][8192];  // per tile: mv1 -> mv2 -> hidden
  __shared__ unsigned int s_sc[2][1024];
  __shared__ float s_ref[2][16];

  const int tid  = threadIdx.x;
  const int lane = tid & 63, wv = tid >> 6;
  const int tr   = lane & 15, u = lane >> 4;
  const int g    = wv >> 1,  h = wv & 1;
  const int tbase = blockIdx.x * 2;

  auto stage_load = [&](const float* __restrict__ src, size_t tok0, int it2, float4* Fr){
    int flat = tid + it2*256;
    int x2 = flat & 31, t = flat >> 5;
    const float* b0 = src + (tok0+t)*1024 + x2*32;
    #pragma unroll
    for (int q=0;q<4;q++){
      Fr[q]   = *(const float4*)(b0 + q*4);
      Fr[4+q] = *(const float4*)(b0 + 16 + q*4);
    }
  };
  auto pack_half = [&](const float4* Fr, unsigned int* P){
    #pragma unroll
    for (int q=0;q<4;q++)
      #pragma unroll
      for (int e=0;e<4;e++)
        P[q*4+e] = pack2(((const float*)&Fr[q])[e], ((const float*)&Fr[4+q])[e]);
  };
  auto stage_write_pk = [&](unsigned int* buf, const unsigned int* P){
    #pragma unroll
    for (int it2=0; it2<2; ++it2){
      int flat = tid + it2*256;
      int x2 = flat & 31, t = flat >> 5;
      unsigned int* dst = &buf[t*32 + (x2 ^ ((t&7)<<2))];
      #pragma unroll
      for (int i=0;i<16;i++) dst[i*512] = P[it2*16 + i];
    }
  };
  auto load_sc_raw = [&](size_t tok0, float* sv){
    #pragma unroll
    for (int it2=0; it2<4; ++it2){
      int flat = tid + it2*256;
      int cp = flat & 63, t = flat >> 6;
      const float* p = (cp<32) ? (sc1 + (tok0+t)*64 + cp*2)
                               : (sc2 + (tok0+t)*64 + (cp-32)*2);
      sv[it2*2+0] = p[0]; sv[it2*2+1] = p[1];
    }
  };
  auto write_sc = [&](unsigned int* scb, const float* sv){
    #pragma unroll
    for (int it2=0; it2<4; ++it2){
      int flat = tid + it2*256;
      int cp = flat & 63, t = flat >> 6;
      scb[t*64 + (cp ^ ((t&7)<<2))] = pack2(sv[it2*2+0], sv[it2*2+1]);
    }
  };

  auto afrag = [&](const unsigned int* buf, int comp, int sh)->s16x8 {
    const unsigned short* p = (const unsigned short*)buf;
    return *(const s16x8*)&p[(comp*16 + tr)*64 + (((sh*4 + u) ^ (tr&7)) << 3)];
  };
  auto scfrag = [&](const unsigned int* scb, int ss)->s16x8 {
    const unsigned short* p = (const unsigned short*)scb;
    return *(const s16x8*)&p[tr*128 + (((ss*4 + u) ^ (tr&7)) << 3)];
  };
  auto slabIn = [&](int m,int d,int s)->s16x8 {
    return *(const s16x8*)&g_WinSlab[((((m*9+d)*2+s)*2+h)*512) + lane*8];
  };
  auto s2In = [&](int m,int s)->s16x8 {
    return *(const s16x8*)&g_WinS2[(((m*2+s)*2+h)*512) + lane*8];
  };
  auto slabOut = [&](int d,int s,int nt)->s16x8 {
    return *(const s16x8*)&g_WoutSlab[(((d*2+s)*4+nt)*512) + lane*8];
  };
  auto s2Out = [&](int ss,int nt)->s16x8 {
    return *(const s16x8*)&g_WoutS2[((ss*4+nt)*512) + lane*8];
  };
  auto bfragS = [&](int s,int nt)->s16x8 {
    return *(const s16x8*)&g_WsB[((s*4+nt)*512) + lane*8];
  };

  // grade-grouped input linear (weights hoisted once per grade)
  auto run_in = [&](const unsigned int* buf, const unsigned int* scb,
                    int m, int scb0, u32x2* accp){
    #pragma unroll
    for (int gr=0; gr<5; ++gr){
      s16x8 w0 = slabIn(m, gr, 0);
      s16x8 w1 = slabIn(m, gr, 1);
      s16x8 p0 = w0, p1 = w1;
      if (gr > 0){ p0 = slabIn(m, gr+4, 0); p1 = slabIn(m, gr+4, 1); }
      #pragma unroll
      for (int c=0; c<GCNT[gr]; ++c){
        const int i = GSTART[gr] + c;
        f32x4 a = (f32x4)0.f;
        a = __builtin_amdgcn_mfma_f32_16x16x32_bf16(afrag(buf,i,0), w0, a,0,0,0);
        a = __builtin_amdgcn_mfma_f32_16x16x32_bf16(afrag(buf,i,1), w1, a,0,0,0);
        if (HASP_[i]){
          a = __builtin_amdgcn_mfma_f32_16x16x32_bf16(afrag(buf,SRC_[i],0), p0, a,0,0,0);
          a = __builtin_amdgcn_mfma_f32_16x16x32_bf16(afrag(buf,SRC_[i],1), p1, a,0,0,0);
        } else if (i==0){
          a = __builtin_amdgcn_mfma_f32_16x16x32_bf16(scfrag(scb,scb0+0), s2In(m,0), a,0,0,0);
          a = __builtin_amdgcn_mfma_f32_16x16x32_bf16(scfrag(scb,scb0+1), s2In(m,1), a,0,0,0);
        }
        accp[i].x = pack2(a[0], a[1]);
        accp[i].y = pack2(a[2], a[3]);
      }
    }
  };

  // ---- prologue: tile0 mv1 + scalars + ref + mv2->PF ----
  unsigned int PF[32];
  {
    size_t tok0 = (size_t)tbase * 16;
    float4 F0[8], F1[8];
    stage_load(mv1, tok0, 0, F0);
    stage_load(mv1, tok0, 1, F1);
    float sv[8];
    load_sc_raw(tok0, sv);
    write_sc(s_sc[0], sv);
    if (tid < 16) s_ref[0][tid] = refmv[(tok0+tid)*16 + 15];
    unsigned int P0[16], P1[16];
    pack_half(F0, P0); pack_half(F1, P1);
    #pragma unroll
    for (int it2=0; it2<2; ++it2){
      int flat = tid + it2*256;
      int x2 = flat & 31, t = flat >> 5;
      unsigned int* dst = &s_mv[0][t*32 + (x2 ^ ((t&7)<<2))];
      const unsigned int* P = it2 ? P1 : P0;
      #pragma unroll
      for (int i=0;i<16;i++) dst[i*512] = P[i];
    }
    float4 F[8];
    stage_load(mv2, tok0, 0, F); pack_half(F, &PF[0]);
    stage_load(mv2, tok0, 1, F); pack_half(F, &PF[16]);
  }
  __syncthreads();

  #pragma unroll
  for (int it = 0; it < 2; ++it){
    const size_t tok0 = (size_t)(tbase + it) * 16;
    unsigned int* bufC = s_mv[it];
    unsigned int* scC  = s_sc[it];

    // it==1: mv2(tile1) load+pack (overlaps stragglers' P3(0); no LDS deps)
    if (it == 1){
      float4 F[8];
      stage_load(mv2, tok0, 0, F); pack_half(F, &PF[0]);
      stage_load(mv2, tok0, 1, F); pack_half(F, &PF[16]);
    }

    // it==0: issue next tile's mv1 + scalars + ref loads; land under P1a
    float4 FN0[8], FN1[8]; float svn[8]; float refn = 0.f;
    if (it == 0){
      size_t tokN = tok0 + 16;
      stage_load(mv1, tokN, 0, FN0);
      stage_load(mv1, tokN, 1, FN1);
      load_sc_raw(tokN, svn);
      if (tid < 16) refn = refmv[(tokN+tid)*16 + 15];
    }

    // ---- P1a: A-side maps from mv1 ----
    u32x2 accAp[16], accBp[16];
    const int mA = (g==0) ? 0 : 2;
    const int mB = (g==0) ? 1 : 3;
    run_in(bufC, scC, mA, 0, accAp);
    __syncthreads();

    // ---- write mv2 into bufC; stage next tile's data into the other buffer ----
    stage_write_pk(bufC, PF);
    if (it == 0){
      unsigned int PN[16];
      pack_half(FN0, PN);
      {
        int x2 = tid & 31, t = tid >> 5;
        unsigned int* dst = &s_mv[1][t*32 + (x2 ^ ((t&7)<<2))];
        #pragma unroll
        for (int i=0;i<16;i++) dst[i*512] = PN[i];
      }
      pack_half(FN1, PN);
      {
        int flat = tid + 256;
        int x2 = flat & 31, t = flat >> 5;
        unsigned int* dst = &s_mv[1][t*32 + (x2 ^ ((t&7)<<2))];
        #pragma unroll
        for (int i=0;i<16;i++) dst[i*512] = PN[i];
      }
      write_sc(s_sc[1], svn);
      if (tid < 16) s_ref[1][tid] = refn;
    }
    __syncthreads();

    // ---- P1c: B-side maps from mv2 ----
    run_in(bufC, scC, mB, 2, accBp);
    __syncthreads();

    // ---- P2: Cayley GP / join; write hidden (aliases bufC) ----
    {
      unsigned short* hidp = (unsigned short*)bufC;
      if (g == 0){
        constexpr GTab CAY = mk_cayley();
        #pragma unroll
        for (int r=0;r<4;r++){
          const int t = u*4 + r;
          float L[16], R[16];
          #pragma unroll
          for (int j2=0;j2<16;j2++){
            unsigned wa = (r&2) ? accAp[j2].y : accAp[j2].x;
            unsigned wb = (r&2) ? accBp[j2].y : accBp[j2].x;
            L[j2] = __uint_as_float((r&1) ? (wa & 0xffff0000u) : (wa << 16));
            R[j2] = __uint_as_float((r&1) ? (wb & 0xffff0000u) : (wb << 16));
          }
          const int c = h*16 + tr;
          #pragma unroll
          for (int i=0;i<16;i++){
            float a = 0.f;
            #pragma unroll
            for (int e=0;e<CAY.cnt[i];e++){
              float p = L[(int)CAY.jj[i][e]] * R[(int)CAY.kk[i][e]];
              a = (CAY.ss[i][e] > 0) ? (a + p) : (a - p);
            }
            hidp[(i*16 + t)*64 + (c ^ ((t&7)<<3))] = f2bfh(a);
          }
        }
      } else {
        constexpr GTab JNT = mk_join();
        #pragma unroll
        for (int r=0;r<4;r++){
          const int t = u*4 + r;
          float rv = s_ref[it][t];
          float L[16], R[16];
          #pragma unroll
          for (int j2=0;j2<16;j2++){
            unsigned wa = (r&2) ? accAp[j2].y : accAp[j2].x;
            unsigned wb = (r&2) ? accBp[j2].y : accBp[j2].x;
            L[j2] = __uint_as_float((r&1) ? (wa & 0xffff0000u) : (wa << 16));
            R[j2] = __uint_as_float((r&1) ? (wb & 0xffff0000u) : (wb << 16));
          }
          const int c = 32 + h*16 + tr;
          #pragma unroll
          for (int i=0;i<16;i++){
            float a = 0.f;
            #pragma unroll
            for (int e=0;e<JNT.cnt[i];e++){
              float p = L[(int)JNT.jj[i][e]] * R[(int)JNT.kk[i][e]];
              a = (JNT.ss[i][e] > 0) ? (a + p) : (a - p);
            }
            hidp[(i*16 + t)*64 + (c ^ ((t&7)<<3))] = f2bfh(a * rv);
          }
        }
      }
    }
    __syncthreads();

    // ---- P3: output equi-linear + scalar head; grade-grouped weights ----
    {
      const int nt = wv;
      f32x4 accO[16]; f32x4 accS = (f32x4)0.f;
      #pragma unroll
      for (int i=0;i<16;i++) accO[i] = (f32x4)0.f;

      #pragma unroll
      for (int gr=0; gr<5; ++gr){
        s16x8 w0 = slabOut(gr, 0, nt);
        s16x8 w1 = slabOut(gr, 1, nt);
        s16x8 p0 = w0, p1 = w1;
        if (gr > 0){ p0 = slabOut(gr+4, 0, nt); p1 = slabOut(gr+4, 1, nt); }
        #pragma unroll
        for (int c=0; c<GCNT[gr]; ++c){
          const int i = GSTART[gr] + c;
          accO[i] = __builtin_amdgcn_mfma_f32_16x16x32_bf16(afrag(bufC,i,0), w0, accO[i],0,0,0);
          accO[i] = __builtin_amdgcn_mfma_f32_16x16x32_bf16(afrag(bufC,i,1), w1, accO[i],0,0,0);
          if (HASP_[i]){
            accO[i] = __builtin_amdgcn_mfma_f32_16x16x32_bf16(afrag(bufC,SRC_[i],0), p0, accO[i],0,0,0);
            accO[i] = __builtin_amdgcn_mfma_f32_16x16x32_bf16(afrag(bufC,SRC_[i],1), p1, accO[i],0,0,0);
          } else if (i==0){
            #pragma unroll
            for (int ss=0;ss<4;ss++)
              accO[0] = __builtin_amdgcn_mfma_f32_16x16x32_bf16(scfrag(scC,ss), s2Out(ss,nt), accO[0],0,0,0);
          }
        }
      }
      accS = __builtin_amdgcn_mfma_f32_16x16x32_bf16(afrag(bufC,0,0), bfragS(0,nt), accS,0,0,0);
      accS = __builtin_amdgcn_mfma_f32_16x16x32_bf16(afrag(bufC,0,1), bfragS(1,nt), accS,0,0,0);
      #pragma unroll
      for (int ss=0;ss<4;ss++)
        accS = __builtin_amdgcn_mfma_f32_16x16x32_bf16(scfrag(scC,ss), bfragS(2+ss,nt), accS,0,0,0);

      const int y = nt*16 + tr;
      const float bv = bias[y];
      #pragma unroll
      for (int r=0;r<4;r++){
        const int t = u*4 + r;
        out[OUT_S_OFF + (tok0+t)*64 + y] = accS[r] + bv;
        float* ob = out + (tok0+t)*1024 + y*16;
        #pragma unroll
        for (int iq=0;iq<4;iq++){
          f32x4 v = { accO[iq*4+0][r], accO[iq*4+1][r], accO[iq*4+2][r], accO[iq*4+3][r] };
          *(f32x4*)(ob + iq*4) = v;
        }
      }
    }
    // no barrier needed between tiles: next P1a reads the OTHER buffer,
    // whose writes were barrier-separated at this tile's mid-point.
  }
}

extern "C" void kernel_launch(void* const* d_in, const int* in_sizes, int n_in,
                              void* d_out, int out_size, void* d_ws, size_t ws_size,
                              hipStream_t stream) {
  const float* mv1   = (const float*)d_in[0];
  const float* mv2   = (const float*)d_in[1];
  const float* sc1   = (const float*)d_in[2];
  const float* sc2   = (const float*)d_in[3];
  const float* refmv = (const float*)d_in[4];
  const float* wL    = (const float*)d_in[5];
  const float* s2L   = (const float*)d_in[6];
  const float* wR    = (const float*)d_in[7];
  const float* s2R   = (const float*)d_in[8];
  const float* wJL   = (const float*)d_in[9];
  const float* s2JL  = (const float*)d_in[10];
  const float* wJR   = (const float*)d_in[11];
  const float* s2JR  = (const float*)d_in[12];
  const float* wO    = (const float*)d_in[13];
  const float* s2O   = (const float*)d_in[14];
  const float* mv2s  = (const float*)d_in[15];
  const float* s2s   = (const float*)d_in[16];
  const float* bias  = (const float*)d_in[17];
  float* out = (float*)d_out;

  prepack<<<17, 256, 0, stream>>>(wL,wR,wJL,wJR,wO, s2L,s2R,s2JL,s2JR, s2O, mv2s, s2s);
  fused<<<1024, 256, 0, stream>>>(mv1, mv2, sc1, sc2, refmv, bias, out);
}

// Round 16
// 138.222 us; speedup vs baseline: 1.1386x; 1.1386x over previous
//
#include <hip/hip_runtime.h>
#include <hip/hip_bf16.h>
#include <cstdint>

#define OUT_S_OFF 33554432ull   // 8*4096*64*16

typedef short s16x8 __attribute__((ext_vector_type(8)));
typedef float f32x4 __attribute__((ext_vector_type(4)));
typedef unsigned int u32x2 __attribute__((ext_vector_type(2)));

// ---------------- compile-time geometric algebra tables ----------------
constexpr int BM_[16]   = {0,1,2,4,8,3,5,9,6,10,12,7,11,13,14,15};
constexpr int IDXm_[16] = {0,1,2,5,3,6,8,11,4,7,9,12,10,13,14,15};
constexpr int G_[16]    = {0,1,1,1,1,2,2,2,2,2,2,3,3,3,3,4};
constexpr int SRC_[16]  = {0,0,2,3,4,2,3,4,8,9,10,8,9,10,14,14};
constexpr int HASP_[16] = {0,1,0,0,0,1,1,1,0,0,0,1,1,1,0,1};
constexpr int A2_[16]   = {0,5,0,0,0,6,6,6,0,0,0,7,7,7,0,8};
constexpr int GSTART[5] = {0,1,5,11,15};
constexpr int GCNT[5]   = {1,4,6,4,1};

constexpr int pcnt_(int x){ int c=0; for(int b=0;b<8;b++) c += (x>>b)&1; return c; }
constexpr int par_(int A,int B){ int sw=0; for(int b=0;b<4;b++) if((B>>b)&1) sw += pcnt_(A>>(b+1)); return (sw&1)?-1:1; }
constexpr int sgnv_(int b){ return par_(BM_[b], 15 & ~BM_[b]); }

struct GTab { int cnt[16]; signed char jj[16][16]; signed char kk[16][16]; signed char ss[16][16]; };

constexpr GTab mk_cayley(){
  GTab t{};
  for(int j=0;j<16;j++) for(int k=0;k<16;k++){
    int A=BM_[j], B=BM_[k];
    if(A & B & 1) continue;
    int i = IDXm_[A^B]; int s = par_(A,B);
    int n = t.cnt[i]; t.jj[i][n]=(signed char)j; t.kk[i][n]=(signed char)k; t.ss[i][n]=(signed char)s; t.cnt[i]=n+1;
  }
  return t;
}
constexpr GTab mk_join(){
  GTab t{};
  for(int j=0;j<16;j++) for(int k=0;k<16;k++){
    int cj = 15 & ~BM_[j], ck = 15 & ~BM_[k];
    if(cj & ck) continue;
    int m  = cj | ck;
    int w  = par_(cj, ck);
    int mp = IDXm_[15 & ~m];
    int s  = sgnv_(j)*sgnv_(k)*w*sgnv_(mp);
    int n = t.cnt[mp]; t.jj[mp][n]=(signed char)j; t.kk[mp][n]=(signed char)k; t.ss[mp][n]=(signed char)s; t.cnt[mp]=n+1;
  }
  return t;
}

__device__ __forceinline__ unsigned short f2bf(float f){   // prepack only
  unsigned u = __float_as_uint(f);
  return (unsigned short)((u + 0x7fffu + ((u>>16)&1u)) >> 16);
}
__device__ __forceinline__ unsigned int pack2(float a, float b){
  float2 v; v.x = a; v.y = b;
  __hip_bfloat162 h = __float22bfloat162_rn(v);
  union { __hip_bfloat162 h2; unsigned int u; } cv; cv.h2 = h; return cv.u;
}
__device__ __forceinline__ unsigned short f2bfh(float f){
  __hip_bfloat16 h = __float2bfloat16(f);
  union { __hip_bfloat16 hb; unsigned short u; } cv; cv.hb = h; return cv.u;
}

// ---------------- slab-indexed prepacked weights (B-operand fragments) ----------------
__device__ unsigned short g_WinSlab [4*9*2*2*512]; // [m][d 0..8][s 0..1][h]  (147KB)
__device__ unsigned short g_WinS2   [4*2*2*512];   // [m][s][h]               (16KB)
__device__ unsigned short g_WoutSlab[9*2*4*512];   // [d][s][nt]              (72KB)
__device__ unsigned short g_WoutS2  [4*4*512];     // [ss][nt]                (16KB)
__device__ unsigned short g_WsB     [6*4*512];     // [s 0..5][nt]            (24KB)

// Coalesced prepack (R15, verified correct): each thread reads contiguous
// 32-288B runs; wave stores land as 1KB contiguous lines per slab. Replaces
// the stride-36B gather version that ran every replay (~10-15us in headline).
__global__ __launch_bounds__(256) void prepack(
    const float* wL, const float* wR, const float* wJL, const float* wJR, const float* wO,
    const float* s2L, const float* s2R, const float* s2JL, const float* s2JR,
    const float* s2O, const float* mv2s, const float* s2s)
{
  int idx = blockIdx.x*256 + threadIdx.x;
  if (idx < 1024) {                          // g_WinSlab: (m,s,h,l) x inner (d,j)
    int l = idx&63, h=(idx>>6)&1, s=(idx>>7)&1, m=(idx>>8)&3;
    int y = h*16 + (l&15), kb = s*32 + ((l>>4)&3)*8;
    const float* w = (m==0)?wL:(m==1)?wR:(m==2)?wJL:wJR;
    unsigned short buf[9][8];
    #pragma unroll
    for (int j=0;j<8;j++){
      const float* src = w + (size_t)(y*64+kb+j)*9;
      #pragma unroll
      for (int d=0;d<9;d++) buf[d][j] = f2bf(src[d]);
    }
    #pragma unroll
    for (int d=0;d<9;d++)
      *(s16x8*)&g_WinSlab[((((m*9+d)*2+s)*2+h)*512) + l*8] = *(const s16x8*)buf[d];
  } else if (idx < 2048) {                   // g_WinS2
    int r = idx-1024;
    int l = r&63, h=(r>>6)&1, s=(r>>7)&1, m=(r>>8)&3;
    int y = h*16 + (l&15), kb = s*32 + ((l>>4)&3)*8;
    const float* s2 = (m==0)?s2L:(m==1)?s2R:(m==2)?s2JL:s2JR;
    unsigned short buf[8];
    #pragma unroll
    for (int j=0;j<8;j++) buf[j] = f2bf(s2[y*64 + kb + j]);
    *(s16x8*)&g_WinS2[(((m*2+s)*2+h)*512) + l*8] = *(const s16x8*)buf;
  } else if (idx < 2560) {                   // g_WoutSlab: (s,nt,l) x inner (d,j)
    int r = idx-2048;
    int l = r&63, nt=(r>>6)&3, s=(r>>8)&1;
    int y = nt*16 + (l&15), kb = s*32 + ((l>>4)&3)*8;
    unsigned short buf[9][8];
    #pragma unroll
    for (int j=0;j<8;j++){
      const float* src = wO + (size_t)(y*64+kb+j)*9;
      #pragma unroll
      for (int d=0;d<9;d++) buf[d][j] = f2bf(src[d]);
    }
    #pragma unroll
    for (int d=0;d<9;d++)
      *(s16x8*)&g_WoutSlab[(((d*2+s)*4+nt)*512) + l*8] = *(const s16x8*)buf[d];
  } else if (idx < 2816) {                   // g_WoutS2: (nt,l) x inner (ss,j)
    int r = idx-2560;
    int l = r&63, nt=(r>>6)&3;
    int y = nt*16 + (l&15), kb = ((l>>4)&3)*8;
    #pragma unroll
    for (int ss=0;ss<4;ss++){
      unsigned short buf[8];
      #pragma unroll
      for (int j=0;j<8;j++) buf[j] = f2bf(s2O[y*128 + ss*32 + kb + j]);
      *(s16x8*)&g_WoutS2[((ss*4+nt)*512) + l*8] = *(const s16x8*)buf;
    }
  } else if (idx < 4352) {                   // g_WsB: (s6,nt,l) x inner j
    int r = idx-2816;
    int l = r&63, nt=(r>>6)&3, s6=r>>8;
    int y = nt*16 + (l&15), kb = ((l>>4)&3)*8;
    unsigned short buf[8];
    #pragma unroll
    for (int j=0;j<8;j++){
      float v = (s6<2) ? mv2s[y*64 + s6*32 + kb + j] : s2s[y*128 + (s6-2)*32 + kb + j];
      buf[j] = f2bf(v);
    }
    *(s16x8*)&g_WsB[((s6*4+nt)*512) + l*8] = *(const s16x8*)buf;
  }
}

// ---------------- fused main kernel (R14 exactly — best clean variant) ----------------
// 256 threads = 4 waves, 16 tokens/block; mv1 in LDS, mv2 prefetched to regs
// (packed bf16) before the first barrier, written into the same buffer after P1a.
// Grade-grouped weight loads (~68 unique weight loads/wave vs 158).
// LESSONS: launch_bounds (256,2) only (tighter spilled R4/6/7/11); token's 64B
// output line stored back-to-back (R9: split => 2.4x write amplification);
// cross-tile prefetch spills — no register headroom (R12/R15).
__global__ __launch_bounds__(256, 2) void fused(
    const float* __restrict__ mv1, const float* __restrict__ mv2,
    const float* __restrict__ sc1, const float* __restrict__ sc2,
    const float* __restrict__ refmv, const float* __restrict__ bias,
    float* __restrict__ out)
{
  __shared__ unsigned int s_mv[8192];   // mv1 -> mv2 -> hidden
  __shared__ unsigned int s_sc[1024];
  __shared__ float s_ref[16];

  const int tid  = threadIdx.x;
  const int lane = tid & 63, wv = tid >> 6;
  const int tr   = lane & 15, u = lane >> 4;
  const int g    = wv >> 1,  h = wv & 1;
  const size_t tok0 = (size_t)blockIdx.x * 16;

  auto stage_load = [&](const float* __restrict__ src, int it, float4* Fr){
    int flat = tid + it*256;
    int x2 = flat & 31, t = flat >> 5;
    const float* b0 = src + (tok0+t)*1024 + x2*32;
    #pragma unroll
    for (int q=0;q<4;q++){
      Fr[q]   = *(const float4*)(b0 + q*4);
      Fr[4+q] = *(const float4*)(b0 + 16 + q*4);
    }
  };
  auto stage_write = [&](int it, const float4* Fr){
    int flat = tid + it*256;
    int x2 = flat & 31, t = flat >> 5;
    unsigned int* dst = &s_mv[t*32 + (x2 ^ ((t&7)<<2))];
    #pragma unroll
    for (int q=0;q<4;q++){
      #pragma unroll
      for (int e=0;e<4;e++){
        int i = q*4 + e;
        dst[i*512] = pack2(((const float*)&Fr[q])[e], ((const float*)&Fr[4+q])[e]);
      }
    }
  };
  auto stage_write_pk = [&](const unsigned int* PF){
    #pragma unroll
    for (int it=0; it<2; ++it){
      int flat = tid + it*256;
      int x2 = flat & 31, t = flat >> 5;
      unsigned int* dst = &s_mv[t*32 + (x2 ^ ((t&7)<<2))];
      #pragma unroll
      for (int i=0;i<16;i++) dst[i*512] = PF[it*16 + i];
    }
  };

  auto afrag = [&](int comp, int sh)->s16x8 {
    const unsigned short* p = (const unsigned short*)s_mv;
    return *(const s16x8*)&p[(comp*16 + tr)*64 + (((sh*4 + u) ^ (tr&7)) << 3)];
  };
  auto scfrag = [&](int ss)->s16x8 {
    const unsigned short* p = (const unsigned short*)s_sc;
    return *(const s16x8*)&p[tr*128 + (((ss*4 + u) ^ (tr&7)) << 3)];
  };
  auto slabIn = [&](int m,int d,int s)->s16x8 {
    return *(const s16x8*)&g_WinSlab[((((m*9+d)*2+s)*2+h)*512) + lane*8];
  };
  auto s2In = [&](int m,int s)->s16x8 {
    return *(const s16x8*)&g_WinS2[(((m*2+s)*2+h)*512) + lane*8];
  };
  auto slabOut = [&](int d,int s,int nt)->s16x8 {
    return *(const s16x8*)&g_WoutSlab[(((d*2+s)*4+nt)*512) + lane*8];
  };
  auto s2Out = [&](int ss,int nt)->s16x8 {
    return *(const s16x8*)&g_WoutS2[((ss*4+nt)*512) + lane*8];
  };
  auto bfragS = [&](int s,int nt)->s16x8 {
    return *(const s16x8*)&g_WsB[((s*4+nt)*512) + lane*8];
  };

  // ---- P0: stage mv1 + scalars + ref; prefetch mv2 to regs BEFORE barrier ----
  unsigned int PF[32];
  {
    float4 F0[8], F1[8];
    stage_load(mv1, 0, F0);
    stage_load(mv1, 1, F1);
    #pragma unroll
    for (int it=0; it<4; ++it){
      int flat = tid + it*256;
      int cp = flat & 63, t = flat >> 6;
      float a, b;
      if (cp < 32){ const float* p = sc1 + (tok0+t)*64 + cp*2;      a=p[0]; b=p[1]; }
      else        { const float* p = sc2 + (tok0+t)*64 + (cp-32)*2; a=p[0]; b=p[1]; }
      s_sc[t*64 + (cp ^ ((t&7)<<2))] = pack2(a,b);
    }
    if (tid < 16) s_ref[tid] = refmv[(tok0+tid)*16 + 15];
    stage_write(0, F0);
    stage_write(1, F1);
    float4 F[8];
    stage_load(mv2, 0, F);
    #pragma unroll
    for (int q=0;q<4;q++)
      #pragma unroll
      for (int e=0;e<4;e++)
        PF[q*4+e] = pack2(((const float*)&F[q])[e], ((const float*)&F[4+q])[e]);
    stage_load(mv2, 1, F);
    #pragma unroll
    for (int q=0;q<4;q++)
      #pragma unroll
      for (int e=0;e<4;e++)
        PF[16+q*4+e] = pack2(((const float*)&F[q])[e], ((const float*)&F[4+q])[e]);
  }
  __syncthreads();

  // ---- grade-grouped input linear (weights hoisted once per grade) ----
  auto run_in = [&](int m, int scb, u32x2* accp){
    #pragma unroll
    for (int gr=0; gr<5; ++gr){
      s16x8 w0 = slabIn(m, gr, 0);
      s16x8 w1 = slabIn(m, gr, 1);
      s16x8 p0 = w0, p1 = w1;
      if (gr > 0){ p0 = slabIn(m, gr+4, 0); p1 = slabIn(m, gr+4, 1); }
      #pragma unroll
      for (int c=0; c<GCNT[gr]; ++c){
        const int i = GSTART[gr] + c;
        f32x4 a = (f32x4)0.f;
        a = __builtin_amdgcn_mfma_f32_16x16x32_bf16(afrag(i,0), w0, a,0,0,0);
        a = __builtin_amdgcn_mfma_f32_16x16x32_bf16(afrag(i,1), w1, a,0,0,0);
        if (HASP_[i]){
          a = __builtin_amdgcn_mfma_f32_16x16x32_bf16(afrag(SRC_[i],0), p0, a,0,0,0);
          a = __builtin_amdgcn_mfma_f32_16x16x32_bf16(afrag(SRC_[i],1), p1, a,0,0,0);
        } else if (i==0){
          a = __builtin_amdgcn_mfma_f32_16x16x32_bf16(scfrag(scb+0), s2In(m,0), a,0,0,0);
          a = __builtin_amdgcn_mfma_f32_16x16x32_bf16(scfrag(scb+1), s2In(m,1), a,0,0,0);
        }
        accp[i].x = pack2(a[0], a[1]);
        accp[i].y = pack2(a[2], a[3]);
      }
    }
  };

  u32x2 accAp[16], accBp[16];
  const int mA = (g==0) ? 0 : 2;
  const int mB = (g==0) ? 1 : 3;

  run_in(mA, 0, accAp);          // P1a from mv1
  __syncthreads();
  stage_write_pk(PF);            // P0b: mv2 into s_mv
  __syncthreads();
  run_in(mB, 2, accBp);          // P1c from mv2
  __syncthreads();

  // ---- P2: Cayley GP / join; write hidden (aliases s_mv) ----
  {
    unsigned short* hidp = (unsigned short*)s_mv;
    if (g == 0){
      constexpr GTab CAY = mk_cayley();
      #pragma unroll
      for (int r=0;r<4;r++){
        const int t = u*4 + r;
        float L[16], R[16];
        #pragma unroll
        for (int j2=0;j2<16;j2++){
          unsigned wa = (r&2) ? accAp[j2].y : accAp[j2].x;
          unsigned wb = (r&2) ? accBp[j2].y : accBp[j2].x;
          L[j2] = __uint_as_float((r&1) ? (wa & 0xffff0000u) : (wa << 16));
          R[j2] = __uint_as_float((r&1) ? (wb & 0xffff0000u) : (wb << 16));
        }
        const int c = h*16 + tr;
        #pragma unroll
        for (int i=0;i<16;i++){
          float a = 0.f;
          #pragma unroll
          for (int e=0;e<CAY.cnt[i];e++){
            float p = L[(int)CAY.jj[i][e]] * R[(int)CAY.kk[i][e]];
            a = (CAY.ss[i][e] > 0) ? (a + p) : (a - p);
          }
          hidp[(i*16 + t)*64 + (c ^ ((t&7)<<3))] = f2bfh(a);
        }
      }
    } else {
      constexpr GTab JNT = mk_join();
      #pragma unroll
      for (int r=0;r<4;r++){
        const int t = u*4 + r;
        float rv = s_ref[t];
        float L[16], R[16];
        #pragma unroll
        for (int j2=0;j2<16;j2++){
          unsigned wa = (r&2) ? accAp[j2].y : accAp[j2].x;
          unsigned wb = (r&2) ? accBp[j2].y : accBp[j2].x;
          L[j2] = __uint_as_float((r&1) ? (wa & 0xffff0000u) : (wa << 16));
          R[j2] = __uint_as_float((r&1) ? (wb & 0xffff0000u) : (wb << 16));
        }
        const int c = 32 + h*16 + tr;
        #pragma unroll
        for (int i=0;i<16;i++){
          float a = 0.f;
          #pragma unroll
          for (int e=0;e<JNT.cnt[i];e++){
            float p = L[(int)JNT.jj[i][e]] * R[(int)JNT.kk[i][e]];
            a = (JNT.ss[i][e] > 0) ? (a + p) : (a - p);
          }
          hidp[(i*16 + t)*64 + (c ^ ((t&7)<<3))] = f2bfh(a * rv);
        }
      }
    }
  }
  __syncthreads();

  // ---- P3: output equi-linear + scalar head; grade-grouped weights ----
  {
    const int nt = wv;
    f32x4 accO[16]; f32x4 accS = (f32x4)0.f;
    #pragma unroll
    for (int i=0;i<16;i++) accO[i] = (f32x4)0.f;

    #pragma unroll
    for (int gr=0; gr<5; ++gr){
      s16x8 w0 = slabOut(gr, 0, nt);
      s16x8 w1 = slabOut(gr, 1, nt);
      s16x8 p0 = w0, p1 = w1;
      if (gr > 0){ p0 = slabOut(gr+4, 0, nt); p1 = slabOut(gr+4, 1, nt); }
      #pragma unroll
      for (int c=0; c<GCNT[gr]; ++c){
        const int i = GSTART[gr] + c;
        accO[i] = __builtin_amdgcn_mfma_f32_16x16x32_bf16(afrag(i,0), w0, accO[i],0,0,0);
        accO[i] = __builtin_amdgcn_mfma_f32_16x16x32_bf16(afrag(i,1), w1, accO[i],0,0,0);
        if (HASP_[i]){
          accO[i] = __builtin_amdgcn_mfma_f32_16x16x32_bf16(afrag(SRC_[i],0), p0, accO[i],0,0,0);
          accO[i] = __builtin_amdgcn_mfma_f32_16x16x32_bf16(afrag(SRC_[i],1), p1, accO[i],0,0,0);
        } else if (i==0){
          #pragma unroll
          for (int ss=0;ss<4;ss++)
            accO[0] = __builtin_amdgcn_mfma_f32_16x16x32_bf16(scfrag(ss), s2Out(ss,nt), accO[0],0,0,0);
        }
      }
    }
    accS = __builtin_amdgcn_mfma_f32_16x16x32_bf16(afrag(0,0), bfragS(0,nt), accS,0,0,0);
    accS = __builtin_amdgcn_mfma_f32_16x16x32_bf16(afrag(0,1), bfragS(1,nt), accS,0,0,0);
    #pragma unroll
    for (int ss=0;ss<4;ss++)
      accS = __builtin_amdgcn_mfma_f32_16x16x32_bf16(scfrag(ss), bfragS(2+ss,nt), accS,0,0,0);

    const int y = nt*16 + tr;
    const float bv = bias[y];
    #pragma unroll
    for (int r=0;r<4;r++){
      const int t = u*4 + r;
      out[OUT_S_OFF + (tok0+t)*64 + y] = accS[r] + bv;
      float* ob = out + (tok0+t)*1024 + y*16;
      #pragma unroll
      for (int iq=0;iq<4;iq++){
        f32x4 v = { accO[iq*4+0][r], accO[iq*4+1][r], accO[iq*4+2][r], accO[iq*4+3][r] };
        *(f32x4*)(ob + iq*4) = v;
      }
    }
  }
}

extern "C" void kernel_launch(void* const* d_in, const int* in_sizes, int n_in,
                              void* d_out, int out_size, void* d_ws, size_t ws_size,
                              hipStream_t stream) {
  const float* mv1   = (const float*)d_in[0];
  const float* mv2   = (const float*)d_in[1];
  const float* sc1   = (const float*)d_in[2];
  const float* sc2   = (const float*)d_in[3];
  const float* refmv = (const float*)d_in[4];
  const float* wL    = (const float*)d_in[5];
  const float* s2L   = (const float*)d_in[6];
  const float* wR    = (const float*)d_in[7];
  const float* s2R   = (const float*)d_in[8];
  const float* wJL   = (const float*)d_in[9];
  const float* s2JL  = (const float*)d_in[10];
  const float* wJR   = (const float*)d_in[11];
  const float* s2JR  = (const float*)d_in[12];
  const float* wO    = (const float*)d_in[13];
  const float* s2O   = (const float*)d_in[14];
  const float* mv2s  = (const float*)d_in[15];
  const float* s2s   = (const float*)d_in[16];
  const float* bias  = (const float*)d_in[17];
  float* out = (float*)d_out;

  prepack<<<17, 256, 0, stream>>>(wL,wR,wJL,wJR,wO, s2L,s2R,s2JL,s2JR, s2O, mv2s, s2s);
  fused<<<2048, 256, 0, stream>>>(mv1, mv2, sc1, sc2, refmv, bias, out);
}